// Round 1
// baseline (235.373 us; speedup 1.0000x reference)
//
#include <hip/hip_runtime.h>
#include <stdint.h>

// SingleHeadAttention: X(4,4096,768) f32; Wq/Wk/Wv(768,64); bq/bk/bv(64)
// out(4,4096,64) f32.  Pipeline: wpack -> proj (MFMA, bf16) -> flash attn (MFMA).
// Workspace use: Qb/Kb/Vt bf16 (3 x 2MB) + Wt bf16 (288KB) + bb f32 (~6.6MB total).

#define QSCALE 0.18033688011112042f  // log2(e)/sqrt(64): fold scale+base2 into Q

using short4v = __attribute__((ext_vector_type(4))) short;
using short8v = __attribute__((ext_vector_type(8))) short;
using float4v = __attribute__((ext_vector_type(4))) float;
using uint4v  = __attribute__((ext_vector_type(4))) unsigned int;

#if __has_builtin(__builtin_amdgcn_exp2f)
#define EXP2F(x) __builtin_amdgcn_exp2f(x)
#else
#define EXP2F(x) exp2f(x)
#endif

__device__ __forceinline__ unsigned short f2b(float f) {
  union { float f; unsigned u; } cv; cv.f = f;
  unsigned u = cv.u;
  u += 0x7FFFu + ((u >> 16) & 1u);   // RNE
  return (unsigned short)(u >> 16);
}

// ---- P0: pack W transposed [n=192][e=768] bf16 (+scaled q part), biases f32 ----
__global__ void wpack_kernel(const float* __restrict__ Wq, const float* __restrict__ bq,
                             const float* __restrict__ Wk, const float* __restrict__ bk,
                             const float* __restrict__ Wv, const float* __restrict__ bv,
                             unsigned short* __restrict__ Wt, float* __restrict__ bb) {
  int gid = blockIdx.x * 256 + threadIdx.x;  // 576*256 == 147456 == 768*192 exactly
  int e = gid / 192, n = gid % 192;
  float v;
  if (n < 64)       v = Wq[e * 64 + n] * QSCALE;
  else if (n < 128) v = Wk[e * 64 + n - 64];
  else              v = Wv[e * 64 + n - 128];
  Wt[n * 768 + e] = f2b(v);
  if (blockIdx.x == 0 && threadIdx.x < 192) {
    int t = threadIdx.x;
    float bvv;
    if (t < 64)       bvv = bq[t] * QSCALE;
    else if (t < 128) bvv = bk[t - 64];
    else              bvv = bv[t - 128];
    bb[t] = bvv;
  }
}

// ---- P1: QKV projection GEMM. 256 blocks x 64 rows, 4 waves, 16x16x32 bf16 MFMA.
// Outputs: Qb[row][64] (scaled), Kb[row][64], Vt[b][64][4096] (transposed V).
__global__ __launch_bounds__(256) void proj_kernel(
    const float* __restrict__ X, const unsigned short* __restrict__ Wt,
    const float* __restrict__ bb,
    unsigned short* __restrict__ Qb, unsigned short* __restrict__ Kb,
    unsigned short* __restrict__ Vt) {
  __shared__ uint4v lds[(8192 + 24576) / 16];
  char* lx = (char*)lds;           // X tile 64x64 bf16, row-XOR swizzled
  char* lw = (char*)lds + 8192;    // W tile 192(n) x 64(k) bf16, row-XOR swizzled
  const int t = threadIdx.x;
  const int w = t >> 6, lane = t & 63, g = lane >> 4, r = lane & 15;
  const int row0 = blockIdx.x * 64;

  float4v acc[3][4];
#pragma unroll
  for (int c = 0; c < 3; ++c) {
    float bias = bb[(w * 3 + c) * 16 + r];
#pragma unroll
    for (int rt = 0; rt < 4; ++rt) acc[c][rt] = {bias, bias, bias, bias};
  }

  const int rr = t >> 2, cs = (t & 3) << 4;
  for (int kc = 0; kc < 12; ++kc) {
    const int k0 = kc * 64;
    __syncthreads();
    {  // stage X chunk: f32 -> bf16, swizzle ^((row&7)<<4) on byte offset
      const float* xp = X + (size_t)(row0 + rr) * 768 + k0 + cs;
#pragma unroll
      for (int q2 = 0; q2 < 4; ++q2) {
        float4v xv = *(const float4v*)(xp + q2 * 4);
        unsigned long long pk =
            (unsigned long long)(f2b(xv[0]) | ((unsigned)f2b(xv[1]) << 16)) |
            ((unsigned long long)(f2b(xv[2]) | ((unsigned)f2b(xv[3]) << 16)) << 32);
        int off = (rr * 128 + (cs + q2 * 4) * 2) ^ ((rr & 7) << 4);
        *(unsigned long long*)(lx + off) = pk;
      }
    }
    if (t < 192) {  // stage W chunk rows n=t, cols k0..k0+63
      const char* wsrc = (const char*)(Wt + t * 768 + k0);
#pragma unroll
      for (int it = 0; it < 8; ++it) {
        int off = (t * 128 + it * 16) ^ ((t & 7) << 4);
        *(uint4v*)(lw + off) = *(const uint4v*)(wsrc + it * 16);
      }
    }
    __syncthreads();

    short8v a[4][2];
#pragma unroll
    for (int rt = 0; rt < 4; ++rt)
#pragma unroll
      for (int ks = 0; ks < 2; ++ks) {
        int row = rt * 16 + r;
        int off = (row * 128 + ks * 64 + g * 16) ^ ((r & 7) << 4);
        a[rt][ks] = *(const short8v*)(lx + off);
      }
#pragma unroll
    for (int c = 0; c < 3; ++c) {
      int n = (w * 3 + c) * 16 + r;
      int ob = (n * 128 + g * 16) ^ ((n & 7) << 4);
      short8v b0 = *(const short8v*)(lw + ob);
      short8v b1 = *(const short8v*)(lw + (ob ^ 64));
#pragma unroll
      for (int rt = 0; rt < 4; ++rt) {
        acc[c][rt] = __builtin_amdgcn_mfma_f32_16x16x32_bf16(a[rt][0], b0, acc[c][rt], 0, 0, 0);
        acc[c][rt] = __builtin_amdgcn_mfma_f32_16x16x32_bf16(a[rt][1], b1, acc[c][rt], 0, 0, 0);
      }
    }
  }
  // epilogue: D mapping row=(lane>>4)*4+i, col=lane&15
#pragma unroll
  for (int c = 0; c < 3; ++c) {
    int n = (w * 3 + c) * 16 + r;
    int mtx = n >> 6, dl = n & 63;
#pragma unroll
    for (int rt = 0; rt < 4; ++rt) {
#pragma unroll
      for (int i = 0; i < 4; ++i) {
        int rg = row0 + rt * 16 + g * 4 + i;
        unsigned short hv = f2b(acc[c][rt][i]);
        if (mtx == 0)      Qb[rg * 64 + dl] = hv;
        else if (mtx == 1) Kb[rg * 64 + dl] = hv;
        else               Vt[(((rg >> 12) << 6) + dl) * 4096 + (rg & 4095)] = hv;
      }
    }
  }
}

// ---- P2: causal flash attention. 1 wave per 16-row Q tile, swapped QK^T. ----
struct KVt { short8v k0, k1; short4v v[4]; };

__global__ __launch_bounds__(64) void attn_kernel(
    const unsigned short* __restrict__ Qb, const unsigned short* __restrict__ Kb,
    const unsigned short* __restrict__ Vt, float* __restrict__ out) {
  const int b = blockIdx.x & 3;
  const int qt = 255 - (blockIdx.x >> 2);  // heavy tiles dispatch first
  const int q0 = qt << 4;
  const int nk = qt + 1;
  const int lane = threadIdx.x;
  const int g = lane >> 4, r = lane & 15;
  const int qidx = q0 + r;

  const unsigned short* qp = Qb + (((b << 12) + q0 + r) << 6) + (g << 3);
  const short8v qf0 = *(const short8v*)qp;
  const short8v qf1 = *(const short8v*)(qp + 32);

  float4v acc[4];
#pragma unroll
  for (int dt = 0; dt < 4; ++dt) acc[dt] = {0.f, 0.f, 0.f, 0.f};
  float mrun = -3.0e38f, lsum = 0.f;

  const unsigned short* kbase = Kb + (((b << 12) + r) << 6) + (g << 3);
  const unsigned short* vbase = Vt + (((b << 6) + r) << 12) + (g << 2);

  auto loadKV = [&](KVt& kv, int kb) {
    const unsigned short* kp = kbase + (kb << 6);
    kv.k0 = *(const short8v*)kp;
    kv.k1 = *(const short8v*)(kp + 32);
    const unsigned short* vp = vbase + kb;
#pragma unroll
    for (int dt = 0; dt < 4; ++dt)
      kv.v[dt] = *(const short4v*)(vp + (dt << 16));  // Vt row stride 4096, 16 rows/dt
  };

  auto step = [&](const KVt& kv, int kb, bool masked) {
    // S^T = K_tile x Q^T : lane holds S[key=4g+i][q=r]; Q pre-scaled to exp2 domain
    float4v s = {0.f, 0.f, 0.f, 0.f};
    s = __builtin_amdgcn_mfma_f32_16x16x32_bf16(kv.k0, qf0, s, 0, 0, 0);
    s = __builtin_amdgcn_mfma_f32_16x16x32_bf16(kv.k1, qf1, s, 0, 0, 0);
    float u0 = s[0], u1 = s[1], u2 = s[2], u3 = s[3];
    if (masked) {
      int k4 = kb + (g << 2);
      u0 = (k4 + 0 <= qidx) ? u0 : -3.0e38f;
      u1 = (k4 + 1 <= qidx) ? u1 : -3.0e38f;
      u2 = (k4 + 2 <= qidx) ? u2 : -3.0e38f;
      u3 = (k4 + 3 <= qidx) ? u3 : -3.0e38f;
    }
    float tmax = fmaxf(fmaxf(u0, u1), fmaxf(u2, u3));
    tmax = fmaxf(tmax, __shfl_xor(tmax, 16));
    tmax = fmaxf(tmax, __shfl_xor(tmax, 32));
    float p0, p1, p2, p3;
    if (__all(tmax <= mrun)) {  // defer-max: skip rescale (common after warmup)
      p0 = EXP2F(u0 - mrun); p1 = EXP2F(u1 - mrun);
      p2 = EXP2F(u2 - mrun); p3 = EXP2F(u3 - mrun);
      lsum += (p0 + p1) + (p2 + p3);
    } else {
      float mn = fmaxf(mrun, tmax);
      float rs = EXP2F(mrun - mn);
      mrun = mn;
      p0 = EXP2F(u0 - mn); p1 = EXP2F(u1 - mn);
      p2 = EXP2F(u2 - mn); p3 = EXP2F(u3 - mn);
      lsum = lsum * rs + ((p0 + p1) + (p2 + p3));
#pragma unroll
      for (int dt = 0; dt < 4; ++dt) acc[dt] *= rs;
    }
    // P^T fragment for PV is exactly the S-tile reg layout: B[k=4g+j][q=r]
    short4v pf;
    pf[0] = (short)f2b(p0); pf[1] = (short)f2b(p1);
    pf[2] = (short)f2b(p2); pf[3] = (short)f2b(p3);
#pragma unroll
    for (int dt = 0; dt < 4; ++dt)
      acc[dt] = __builtin_amdgcn_mfma_f32_16x16x16bf16_1k(kv.v[dt], pf, acc[dt], 0, 0, 0);
  };

  KVt bufA, bufB;  // register double-buffer so next tile's loads hide under compute
  loadKV(bufA, 0);
  int t = 0;
  while (true) {
    if (t + 1 < nk) loadKV(bufB, (t + 1) << 4);
    step(bufA, t << 4, t == nk - 1);
    if (++t >= nk) break;
    if (t + 1 < nk) loadKV(bufA, (t + 1) << 4);
    step(bufB, t << 4, t == nk - 1);
    if (++t >= nk) break;
  }

  lsum += __shfl_xor(lsum, 16);
  lsum += __shfl_xor(lsum, 32);
  float inv = 1.0f / lsum;
  float* op = out + (((b << 12) + q0 + r) << 6) + (g << 2);
#pragma unroll
  for (int dt = 0; dt < 4; ++dt) {
    float4v o = acc[dt] * inv;
    *(float4v*)(op + (dt << 4)) = o;  // O[q][d]: acc regs i are contiguous d
  }
}

extern "C" void kernel_launch(void* const* d_in, const int* in_sizes, int n_in,
                              void* d_out, int out_size, void* d_ws, size_t ws_size,
                              hipStream_t stream) {
  const float* X  = (const float*)d_in[0];
  const float* Wq = (const float*)d_in[1];
  const float* bq = (const float*)d_in[2];
  const float* Wk = (const float*)d_in[3];
  const float* bk = (const float*)d_in[4];
  const float* Wv = (const float*)d_in[5];
  const float* bv = (const float*)d_in[6];
  float* out = (float*)d_out;

  unsigned short* Qb = (unsigned short*)d_ws;        // [B*S][64] bf16 (scaled)
  unsigned short* Kb = Qb + 4 * 4096 * 64;           // [B*S][64] bf16
  unsigned short* Vt = Kb + 4 * 4096 * 64;           // [B][64][S] bf16
  unsigned short* Wt = Vt + 4 * 4096 * 64;           // [192][768] bf16
  float* bb = (float*)(Wt + 192 * 768);              // [192] f32

  wpack_kernel<<<576, 256, 0, stream>>>(Wq, bq, Wk, bk, Wv, bv, Wt, bb);
  proj_kernel<<<256, 256, 0, stream>>>(X, Wt, bb, Qb, Kb, Vt);
  attn_kernel<<<1024, 64, 0, stream>>>(Qb, Kb, Vt, out);
}

// Round 2
// 232.033 us; speedup vs baseline: 1.0144x; 1.0144x over previous
//
#include <hip/hip_runtime.h>
#include <stdint.h>

// SingleHeadAttention: X(4,4096,768) f32; Wq/Wk/Wv(768,64); bq/bk/bv(64)
// out(4,4096,64) f32.
// Pipeline: wpack (LDS transpose) -> proj (MFMA bf16, 512 blocks) ->
//           flash attn SPLIT-K (4608 waves, partials) -> combine.

#define QSCALE 0.18033688011112042f  // log2(e)/sqrt(64): fold scale+base2 into Q
#define SC 32                        // steps (16 keys each) per split chunk = 512 keys
#define NSLOT 1152                   // sum_{qt=0..255} ceil((qt+1)/32) per batch

using short4v = __attribute__((ext_vector_type(4))) short;
using short8v = __attribute__((ext_vector_type(8))) short;
using float4v = __attribute__((ext_vector_type(4))) float;
using uint4v  = __attribute__((ext_vector_type(4))) unsigned int;
typedef unsigned long long ull;
typedef unsigned short ushort;

#if __has_builtin(__builtin_amdgcn_exp2f)
#define EXP2F(x) __builtin_amdgcn_exp2f(x)
#else
#define EXP2F(x) exp2f(x)
#endif

__device__ __forceinline__ ushort f2b(float f) {
  union { float f; unsigned u; } cv; cv.f = f;
  unsigned u = cv.u;
  u += 0x7FFFu + ((u >> 16) & 1u);   // RNE
  return (ushort)(u >> 16);
}
__device__ __forceinline__ ull pack4(float4v v) {
  return (ull)(f2b(v[0]) | ((unsigned)f2b(v[1]) << 16)) |
         ((ull)(f2b(v[2]) | ((unsigned)f2b(v[3]) << 16)) << 32);
}
// sum_{i=1..qt} ceil(i/32): partial-slot base for q-tile qt
__device__ __forceinline__ int fbase(int qt) {
  int a = qt >> 5, rm = qt & 31;
  return 16 * a * (a + 1) + rm * (a + 1);
}

// ---- P0: pack W transposed [n=192][e=768] bf16 via LDS bounce; biases f32 ----
__global__ void wpack_kernel(const float* __restrict__ Wq, const float* __restrict__ bq,
                             const float* __restrict__ Wk, const float* __restrict__ bk,
                             const float* __restrict__ Wv, const float* __restrict__ bv,
                             ushort* __restrict__ Wt, float* __restrict__ bb) {
  __shared__ float tile[64 * 65];
  const int t = threadIdx.x;
  const int m = blockIdx.x % 3, e0 = (blockIdx.x / 3) * 64;
  const float* Wsrc = (m == 0) ? Wq : (m == 1) ? Wk : Wv;
  const float sc = (m == 0) ? QSCALE : 1.0f;
#pragma unroll
  for (int i = 0; i < 16; ++i) {   // load: consecutive t -> consecutive n (coalesced)
    int idx = i * 256 + t, n = idx & 63, el = idx >> 6;
    tile[el * 65 + n] = Wsrc[(size_t)(e0 + el) * 64 + n];
  }
  __syncthreads();
#pragma unroll
  for (int i = 0; i < 16; ++i) {   // store: consecutive t -> consecutive e (coalesced)
    int idx = i * 256 + t, el = idx & 63, n = idx >> 6;
    Wt[(size_t)(m * 64 + n) * 768 + e0 + el] = f2b(tile[el * 65 + n] * sc);
  }
  if (blockIdx.x == 0 && t < 192) {
    float bvv;
    if (t < 64)       bvv = bq[t] * QSCALE;
    else if (t < 128) bvv = bk[t - 64];
    else              bvv = bv[t - 128];
    bb[t] = bvv;
  }
}

// ---- P1: QKV projection GEMM. 512 blocks x 32 rows, 4 waves, 16x16x32 bf16. ----
__global__ __launch_bounds__(256) void proj_kernel(
    const float* __restrict__ X, const ushort* __restrict__ Wt,
    const float* __restrict__ bb,
    ushort* __restrict__ Qb, ushort* __restrict__ Kb, ushort* __restrict__ Vt) {
  __shared__ char lds[4096 + 24576];
  char* lx = lds;          // X tile 32x64 bf16, row-XOR swizzled
  char* lw = lds + 4096;   // W tile 192(n) x 64(k) bf16, row-XOR swizzled
  const int t = threadIdx.x;
  const int w = t >> 6, lane = t & 63, g = lane >> 4, r = lane & 15;
  const int row0 = blockIdx.x * 32;

  float4v acc[3][2];
#pragma unroll
  for (int c = 0; c < 3; ++c) {
    float bias = bb[w * 48 + c * 16 + r];
#pragma unroll
    for (int rt = 0; rt < 2; ++rt) acc[c][rt] = {bias, bias, bias, bias};
  }

  const int rr = t >> 3, cs = (t & 7) << 3;  // X staging: 8 f32 per thread
  for (int kc = 0; kc < 12; ++kc) {
    const int k0 = kc * 64;
    __syncthreads();
    {  // stage X chunk: f32 -> bf16, swizzle ^((row&7)<<4)
      const float* xp = X + (size_t)(row0 + rr) * 768 + k0 + cs;
      float4v x0 = *(const float4v*)xp;
      float4v x1 = *(const float4v*)(xp + 4);
      int o0 = (rr * 128 + cs * 2) ^ ((rr & 7) << 4);
      *(ull*)(lx + o0) = pack4(x0);
      *(ull*)(lx + o0 + 8) = pack4(x1);
    }
#pragma unroll
    for (int it = 0; it < 6; ++it) {  // stage W chunk: 1536 16B segs, coalesced
      int fi = it * 256 + t;
      int wr = fi >> 3, seg = fi & 7;
      int off = (wr * 128 + seg * 16) ^ ((wr & 7) << 4);
      *(uint4v*)(lw + off) =
          *(const uint4v*)((const char*)(Wt + (size_t)wr * 768 + k0) + seg * 16);
    }
    __syncthreads();

    short8v a[2][2];
#pragma unroll
    for (int rt = 0; rt < 2; ++rt)
#pragma unroll
      for (int ks = 0; ks < 2; ++ks) {
        int row = rt * 16 + r;
        int off = (row * 128 + ks * 64 + g * 16) ^ ((row & 7) << 4);
        a[rt][ks] = *(const short8v*)(lx + off);
      }
#pragma unroll
    for (int c = 0; c < 3; ++c) {
      int n = w * 48 + c * 16 + r;
      int ob = (n * 128 + g * 16) ^ ((n & 7) << 4);
      short8v b0 = *(const short8v*)(lw + ob);
      short8v b1 = *(const short8v*)(lw + (ob ^ 64));
#pragma unroll
      for (int rt = 0; rt < 2; ++rt) {
        acc[c][rt] = __builtin_amdgcn_mfma_f32_16x16x32_bf16(a[rt][0], b0, acc[c][rt], 0, 0, 0);
        acc[c][rt] = __builtin_amdgcn_mfma_f32_16x16x32_bf16(a[rt][1], b1, acc[c][rt], 0, 0, 0);
      }
    }
  }
#pragma unroll
  for (int c = 0; c < 3; ++c) {
    int n = w * 48 + c * 16 + r;
    int mtx = n >> 6, dl = n & 63;
#pragma unroll
    for (int rt = 0; rt < 2; ++rt) {
#pragma unroll
      for (int i = 0; i < 4; ++i) {
        int rg = row0 + rt * 16 + g * 4 + i;
        ushort hv = f2b(acc[c][rt][i]);
        if (mtx == 0)      Qb[rg * 64 + dl] = hv;
        else if (mtx == 1) Kb[rg * 64 + dl] = hv;
        else               Vt[(size_t)(((rg >> 12) << 6) + dl) * 4096 + (rg & 4095)] = hv;
      }
    }
  }
}

// ---- P2: causal flash attention, SPLIT-K over 512-key chunks. ----
struct KVt { short8v k0, k1; short4v v[4]; };

__global__ __launch_bounds__(64) void attn_kernel(
    const ushort* __restrict__ Qb, const ushort* __restrict__ Kb,
    const ushort* __restrict__ Vt, float* __restrict__ pacc, float* __restrict__ pml) {
  const int b = blockIdx.x & 3;
  const int qt = 255 - (blockIdx.x >> 2);  // heavy tiles dispatch first
  const int c = blockIdx.y;
  const int nc = (qt >> 5) + 1;            // ceil((qt+1)/32)
  if (c >= nc) return;
  const int s0 = c << 5;
  const int s1 = min(s0 + SC, qt + 1);
  const int q0 = qt << 4;
  const int lane = threadIdx.x;
  const int g = lane >> 4, r = lane & 15;
  const int qidx = q0 + r;

  const ushort* qp = Qb + (((b << 12) + q0 + r) << 6) + (g << 3);
  const short8v qf0 = *(const short8v*)qp;
  const short8v qf1 = *(const short8v*)(qp + 32);

  float4v acc[4];
#pragma unroll
  for (int dt = 0; dt < 4; ++dt) acc[dt] = {0.f, 0.f, 0.f, 0.f};
  float mrun = -3.0e38f, lsum = 0.f;

  const ushort* kbase = Kb + (((b << 12) + r) << 6) + (g << 3);
  const ushort* vbase = Vt + (((b << 6) + r) << 12) + (g << 2);

  auto loadKV = [&](KVt& kv, int kb) {
    const ushort* kp = kbase + (kb << 6);
    kv.k0 = *(const short8v*)kp;
    kv.k1 = *(const short8v*)(kp + 32);
    const ushort* vp = vbase + kb;
#pragma unroll
    for (int dt = 0; dt < 4; ++dt)
      kv.v[dt] = *(const short4v*)(vp + (dt << 16));  // Vt row stride 4096
  };

  auto step = [&](const KVt& kv, int kb, bool masked) {
    // S^T = K_tile x Q^T : lane holds S[key=4g+i][q=r]; Q pre-scaled (exp2 domain)
    float4v s = {0.f, 0.f, 0.f, 0.f};
    s = __builtin_amdgcn_mfma_f32_16x16x32_bf16(kv.k0, qf0, s, 0, 0, 0);
    s = __builtin_amdgcn_mfma_f32_16x16x32_bf16(kv.k1, qf1, s, 0, 0, 0);
    float u0 = s[0], u1 = s[1], u2 = s[2], u3 = s[3];
    if (masked) {
      int k4 = kb + (g << 2);
      u0 = (k4 + 0 <= qidx) ? u0 : -3.0e38f;
      u1 = (k4 + 1 <= qidx) ? u1 : -3.0e38f;
      u2 = (k4 + 2 <= qidx) ? u2 : -3.0e38f;
      u3 = (k4 + 3 <= qidx) ? u3 : -3.0e38f;
    }
    float tmax = fmaxf(fmaxf(u0, u1), fmaxf(u2, u3));
    tmax = fmaxf(tmax, __shfl_xor(tmax, 16));
    tmax = fmaxf(tmax, __shfl_xor(tmax, 32));
    float p0, p1, p2, p3;
    if (__all(tmax <= mrun)) {  // defer-max: skip rescale
      p0 = EXP2F(u0 - mrun); p1 = EXP2F(u1 - mrun);
      p2 = EXP2F(u2 - mrun); p3 = EXP2F(u3 - mrun);
      lsum += (p0 + p1) + (p2 + p3);
    } else {
      float mn = fmaxf(mrun, tmax);
      float rs = EXP2F(mrun - mn);
      mrun = mn;
      p0 = EXP2F(u0 - mn); p1 = EXP2F(u1 - mn);
      p2 = EXP2F(u2 - mn); p3 = EXP2F(u3 - mn);
      lsum = lsum * rs + ((p0 + p1) + (p2 + p3));
#pragma unroll
      for (int dt = 0; dt < 4; ++dt) acc[dt] *= rs;
    }
    short4v pf;
    pf[0] = (short)f2b(p0); pf[1] = (short)f2b(p1);
    pf[2] = (short)f2b(p2); pf[3] = (short)f2b(p3);
#pragma unroll
    for (int dt = 0; dt < 4; ++dt)
      acc[dt] = __builtin_amdgcn_mfma_f32_16x16x16bf16_1k(kv.v[dt], pf, acc[dt], 0, 0, 0);
  };

  KVt bufA, bufB;  // register double-buffer
  loadKV(bufA, s0 << 4);
  int t = s0;
  while (true) {
    if (t + 1 < s1) loadKV(bufB, (t + 1) << 4);
    step(bufA, t << 4, t == qt);
    if (++t >= s1) break;
    if (t + 1 < s1) loadKV(bufA, (t + 1) << 4);
    step(bufB, t << 4, t == qt);
    if (++t >= s1) break;
  }

  lsum += __shfl_xor(lsum, 16);
  lsum += __shfl_xor(lsum, 32);

  const int slot = b * NSLOT + fbase(qt) + c;
  if (g == 0) {
    pml[slot * 32 + r * 2 + 0] = mrun;
    pml[slot * 32 + r * 2 + 1] = lsum;
  }
  float* pp = pacc + slot * 1024 + r * 64 + (g << 2);
#pragma unroll
  for (int dt = 0; dt < 4; ++dt)
    *(float4v*)(pp + (dt << 4)) = acc[dt];  // [row=r][d=16dt+4g+i]
}

// ---- P3: combine split-K partials ----
__global__ __launch_bounds__(256) void combine_kernel(
    const float* __restrict__ pacc, const float* __restrict__ pml,
    float* __restrict__ out) {
  const int b = blockIdx.x & 3;
  const int qt = blockIdx.x >> 2;
  const int nc = (qt >> 5) + 1;
  const int sbase = b * NSLOT + fbase(qt);
  const int t = threadIdx.x;
  const int row = t >> 4, d0 = (t & 15) << 2;

  float M = -3.0e38f;
  float ms[8];
#pragma unroll 8
  for (int p = 0; p < nc; ++p) {
    ms[p] = pml[(sbase + p) * 32 + row * 2];
    M = fmaxf(M, ms[p]);
  }
  float denom = 0.f;
  float4v val = {0.f, 0.f, 0.f, 0.f};
#pragma unroll 8
  for (int p = 0; p < nc; ++p) {
    float wgt = EXP2F(ms[p] - M);
    denom += pml[(sbase + p) * 32 + row * 2 + 1] * wgt;
    float4v a = *(const float4v*)(pacc + (size_t)(sbase + p) * 1024 + row * 64 + d0);
    val += a * wgt;
  }
  float inv = 1.0f / denom;
  *(float4v*)(out + (size_t)((b << 12) + (qt << 4) + row) * 64 + d0) = val * inv;
}

extern "C" void kernel_launch(void* const* d_in, const int* in_sizes, int n_in,
                              void* d_out, int out_size, void* d_ws, size_t ws_size,
                              hipStream_t stream) {
  const float* X  = (const float*)d_in[0];
  const float* Wq = (const float*)d_in[1];
  const float* bq = (const float*)d_in[2];
  const float* Wk = (const float*)d_in[3];
  const float* bk = (const float*)d_in[4];
  const float* Wv = (const float*)d_in[5];
  const float* bv = (const float*)d_in[6];
  float* out = (float*)d_out;

  ushort* Qb = (ushort*)d_ws;                  // [B*S][64] bf16 (scaled, exp2 domain)
  ushort* Kb = Qb + 4 * 4096 * 64;             // [B*S][64] bf16
  ushort* Vt = Kb + 4 * 4096 * 64;             // [B][64][S] bf16
  ushort* Wt = Vt + 4 * 4096 * 64;             // [192][768] bf16
  float* bb  = (float*)(Wt + 192 * 768);       // [192] f32
  float* pml  = bb + 256;                      // [4*1152][16][2] f32
  float* pacc = pml + 4 * NSLOT * 32;          // [4*1152][16][64] f32 (~18.9MB)

  wpack_kernel<<<36, 256, 0, stream>>>(Wq, bq, Wk, bk, Wv, bv, Wt, bb);
  proj_kernel<<<512, 256, 0, stream>>>(X, Wt, bb, Qb, Kb, Vt);
  attn_kernel<<<dim3(1024, 8), 64, 0, stream>>>(Qb, Kb, Vt, pacc, pml);
  combine_kernel<<<1024, 256, 0, stream>>>(pacc, pml, out);
}

// Round 3
// 158.895 us; speedup vs baseline: 1.4813x; 1.4603x over previous
//
#include <hip/hip_runtime.h>
#include <stdint.h>

// SingleHeadAttention: X(4,4096,768) f32; Wq/Wk/Wv(768,64); bq/bk/bv(64)
// out(4,4096,64) f32.
// wpack -> proj (MFMA bf16, dbuf) -> attn (8-wave blocks, LDS-shared K/V,
// split-K 512-key chunks) -> combine (no-scratch, 2-pass).

#define QSCALE 0.18033688011112042f  // log2(e)/sqrt(64): fold scale+base2 into Q

using short4v = __attribute__((ext_vector_type(4))) short;
using short8v = __attribute__((ext_vector_type(8))) short;
using float4v = __attribute__((ext_vector_type(4))) float;
using uint4v  = __attribute__((ext_vector_type(4))) unsigned int;
typedef unsigned long long ull;
typedef unsigned short ushort;

#if __has_builtin(__builtin_amdgcn_exp2f)
#define EXP2F(x) __builtin_amdgcn_exp2f(x)
#else
#define EXP2F(x) exp2f(x)
#endif

__device__ __forceinline__ ushort f2b(float f) {
  union { float f; unsigned u; } cv; cv.f = f;
  unsigned u = cv.u;
  u += 0x7FFFu + ((u >> 16) & 1u);   // RNE
  return (ushort)(u >> 16);
}

// ---- P0: pack W transposed [n=192][e=768] bf16 via LDS bounce; biases f32 ----
__global__ void wpack_kernel(const float* __restrict__ Wq, const float* __restrict__ bq,
                             const float* __restrict__ Wk, const float* __restrict__ bk,
                             const float* __restrict__ Wv, const float* __restrict__ bv,
                             ushort* __restrict__ Wt, float* __restrict__ bb) {
  __shared__ float tile[64 * 65];
  const int t = threadIdx.x;
  const int m = blockIdx.x % 3, e0 = (blockIdx.x / 3) * 64;
  const float* Wsrc = (m == 0) ? Wq : (m == 1) ? Wk : Wv;
  const float sc = (m == 0) ? QSCALE : 1.0f;
#pragma unroll
  for (int i = 0; i < 16; ++i) {
    int idx = i * 256 + t, n = idx & 63, el = idx >> 6;
    tile[el * 65 + n] = Wsrc[(size_t)(e0 + el) * 64 + n];
  }
  __syncthreads();
#pragma unroll
  for (int i = 0; i < 16; ++i) {
    int idx = i * 256 + t, el = idx & 63, n = idx >> 6;
    Wt[(size_t)(m * 64 + n) * 768 + e0 + el] = f2b(tile[el * 65 + n] * sc);
  }
  if (blockIdx.x == 0 && t < 192) {
    float bvv;
    if (t < 64)       bvv = bq[t] * QSCALE;
    else if (t < 128) bvv = bk[t - 64];
    else              bvv = bv[t - 128];
    bb[t] = bvv;
  }
}

// ---- P1: QKV projection. 512 blocks x 32 rows, dbuf X-LDS, W frags from L2. ----
__global__ __launch_bounds__(256) void proj_kernel(
    const float* __restrict__ X, const ushort* __restrict__ Wt,
    const float* __restrict__ bb,
    ushort* __restrict__ Qb, ushort* __restrict__ Kb, ushort* __restrict__ Vt) {
  __shared__ char lx[2][4096];  // X tile 32x64 bf16, ^((row&7)<<4)
  const int t = threadIdx.x;
  const int wv = t >> 6, lane = t & 63, g = lane >> 4, r = lane & 15;
  const int row0 = blockIdx.x * 32;

  float4v acc[3][2];
#pragma unroll
  for (int ct = 0; ct < 3; ++ct) {
    float bias = bb[wv * 48 + ct * 16 + r];
#pragma unroll
    for (int rt = 0; rt < 2; ++rt) acc[ct][rt] = {bias, bias, bias, bias};
  }

  const int rr = t >> 3, sg = t & 7;
  const float* xbase = X + (size_t)(row0 + rr) * 768 + sg * 8;
  const ushort* wbase = Wt + (size_t)(wv * 48 + r) * 768 + g * 8;
  const int xoff = (rr * 128 + sg * 16) ^ ((rr & 7) << 4);

  float4v xh0, xh1, xn0, xn1;
  short8v wcur[6], wnxt[6];

  {  // prologue
    xh0 = *(const float4v*)xbase;
    xh1 = *(const float4v*)(xbase + 4);
#pragma unroll
    for (int ct = 0; ct < 3; ++ct)
#pragma unroll
      for (int ks = 0; ks < 2; ++ks)
        wcur[ct * 2 + ks] = *(const short8v*)(wbase + ct * 16 * 768 + ks * 32);
    uint4v pk;
    pk[0] = f2b(xh0[0]) | ((unsigned)f2b(xh0[1]) << 16);
    pk[1] = f2b(xh0[2]) | ((unsigned)f2b(xh0[3]) << 16);
    pk[2] = f2b(xh1[0]) | ((unsigned)f2b(xh1[1]) << 16);
    pk[3] = f2b(xh1[2]) | ((unsigned)f2b(xh1[3]) << 16);
    *(uint4v*)(lx[0] + xoff) = pk;
    xh0 = *(const float4v*)(xbase + 64);
    xh1 = *(const float4v*)(xbase + 68);
  }
  __syncthreads();

#pragma unroll
  for (int kc = 0; kc < 12; ++kc) {
    if (kc + 2 < 12) {
      xn0 = *(const float4v*)(xbase + (kc + 2) * 64);
      xn1 = *(const float4v*)(xbase + (kc + 2) * 64 + 4);
    }
    if (kc + 1 < 12) {
#pragma unroll
      for (int ct = 0; ct < 3; ++ct)
#pragma unroll
        for (int ks = 0; ks < 2; ++ks)
          wnxt[ct * 2 + ks] =
              *(const short8v*)(wbase + ct * 16 * 768 + (kc + 1) * 64 + ks * 32);
    }
    short8v a[2][2];
#pragma unroll
    for (int rt = 0; rt < 2; ++rt)
#pragma unroll
      for (int ks = 0; ks < 2; ++ks) {
        int off = ((rt * 16 + r) * 128 + ks * 64 + g * 16) ^ ((r & 7) << 4);
        a[rt][ks] = *(const short8v*)(lx[kc & 1] + off);
      }
#pragma unroll
    for (int ct = 0; ct < 3; ++ct)
#pragma unroll
      for (int rt = 0; rt < 2; ++rt) {
        acc[ct][rt] = __builtin_amdgcn_mfma_f32_16x16x32_bf16(a[rt][0], wcur[ct * 2 + 0], acc[ct][rt], 0, 0, 0);
        acc[ct][rt] = __builtin_amdgcn_mfma_f32_16x16x32_bf16(a[rt][1], wcur[ct * 2 + 1], acc[ct][rt], 0, 0, 0);
      }
    if (kc + 1 < 12) {
      uint4v pk;
      pk[0] = f2b(xh0[0]) | ((unsigned)f2b(xh0[1]) << 16);
      pk[1] = f2b(xh0[2]) | ((unsigned)f2b(xh0[3]) << 16);
      pk[2] = f2b(xh1[0]) | ((unsigned)f2b(xh1[1]) << 16);
      pk[3] = f2b(xh1[2]) | ((unsigned)f2b(xh1[3]) << 16);
      *(uint4v*)(lx[(kc + 1) & 1] + xoff) = pk;
    }
    __syncthreads();
    xh0 = xn0; xh1 = xn1;
#pragma unroll
    for (int i = 0; i < 6; ++i) wcur[i] = wnxt[i];
  }
#pragma unroll
  for (int ct = 0; ct < 3; ++ct) {
    int n = wv * 48 + ct * 16 + r;
    int mtx = n >> 6, dl = n & 63;
#pragma unroll
    for (int rt = 0; rt < 2; ++rt) {
#pragma unroll
      for (int i = 0; i < 4; ++i) {
        int rg = row0 + rt * 16 + g * 4 + i;
        ushort hv = f2b(acc[ct][rt][i]);
        if (mtx == 0)      Qb[rg * 64 + dl] = hv;
        else if (mtx == 1) Kb[rg * 64 + dl] = hv;
        else               Vt[(size_t)(((rg >> 12) << 6) + dl) * 4096 + (rg & 4095)] = hv;
      }
    }
  }
}

// ---- P2: flash attn. 8-wave blocks (128 q-rows), LDS K/V 64-key macro-tiles,
//          double-buffered; split-K chunks of 512 keys. 576 blocks total. ----
__global__ __launch_bounds__(512) void attn_kernel(
    const ushort* __restrict__ Qb, const ushort* __restrict__ Kb,
    const ushort* __restrict__ Vt, float* __restrict__ pacc, float* __restrict__ pml) {
  __shared__ char lds[32768];
  char* lk = lds;            // [2][64 key][128B], ^((key&7)<<4)
  char* lv = lds + 16384;    // [2][4 ks][64 d][4 slots*8B], slot^((d>>2)&3)
  const int t = threadIdx.x;
  const int wv = t >> 6, lane = t & 63, g = lane >> 4, r = lane & 15;
  const int bx = blockIdx.x;
  const int b = bx / 144;
  int rem = bx - b * 144;
  int g2 = 0;
  while (2 * (g2 + 1) * (g2 + 2) <= rem) ++g2;
  int rem2 = rem - 2 * g2 * (g2 + 1);
  int q_ = rem2 / (g2 + 1);
  const int st = 4 * g2 + q_;
  const int c = rem2 - q_ * (g2 + 1);

  const int s0 = c * 32;                        // chunk base step (16-key steps)
  const int smax = min(32, 8 * st + 8 - s0);    // steps staged (always mult of 4)
  const int nm = smax >> 2;                     // 64-key macro tiles
  const int mysteps = min(8 * st + wv + 1 - s0, smax);  // <=0 -> idle wave
  const int dloc = 8 * st + wv - s0;            // local diag step (mask only there)

  const size_t qoff = ((size_t)(b * 4096 + st * 128 + wv * 16 + r)) * 64 + g * 8;
  const short8v qf0 = *(const short8v*)(Qb + qoff);
  const short8v qf1 = *(const short8v*)(Qb + qoff + 32);

  float4v acc[4];
#pragma unroll
  for (int dt = 0; dt < 4; ++dt) acc[dt] = {0.f, 0.f, 0.f, 0.f};
  float mrun = -3.0e38f, lsum = 0.f;

  // staging addresses (thread t stages K row kr seg sg, and V d-row kr seg sg)
  const int kr = t >> 3, sg = t & 7;
  const ushort* ksrc = Kb + ((size_t)(b * 4096 + c * 512 + kr)) * 64 + sg * 8;
  const ushort* vsrc = Vt + ((size_t)(b * 64 + kr)) * 4096 + c * 512 + sg * 8;
  const int kwoff = (kr * 128 + sg * 16) ^ ((kr & 7) << 4);
  const int wsw = (kr >> 2) & 3;
  const int vwbase = (sg >> 1) * 2048 + kr * 32;
  const int vs0 = (((sg & 1) * 2) ^ wsw) * 8, vs1 = (((sg & 1) * 2 + 1) ^ wsw) * 8;

  uint4v kR1, vR1, kR2, vR2;
  auto stload = [&](int m, uint4v& kk, uint4v& vvv) {
    kk  = *(const uint4v*)(ksrc + (size_t)m * 64 * 64);
    vvv = *(const uint4v*)(vsrc + m * 64);
  };
  auto stwrite = [&](int bi, uint4v kk, uint4v vvv) {
    *(uint4v*)(lk + bi * 8192 + kwoff) = kk;
    char* vb = lv + bi * 8192 + vwbase;
    *(ull*)(vb + vs0) = (ull)vvv[0] | ((ull)vvv[1] << 32);
    *(ull*)(vb + vs1) = (ull)vvv[2] | ((ull)vvv[3] << 32);
  };

  auto micro = [&](int bi, int ks, bool masked) {
    const char* lkb = lk + bi * 8192;
    const char* lvb = lv + bi * 8192 + ks * 2048;
    const int krow = ks * 16 + r;
    const int ksw = (r & 7) << 4;
    const short8v k0 = *(const short8v*)(lkb + ((krow * 128 + g * 16) ^ ksw));
    const short8v k1 = *(const short8v*)(lkb + ((krow * 128 + g * 16 + 64) ^ ksw));
    float4v s = {0.f, 0.f, 0.f, 0.f};
    s = __builtin_amdgcn_mfma_f32_16x16x32_bf16(k0, qf0, s, 0, 0, 0);
    s = __builtin_amdgcn_mfma_f32_16x16x32_bf16(k1, qf1, s, 0, 0, 0);
    float u0 = s[0], u1 = s[1], u2 = s[2], u3 = s[3];
    if (masked) {  // diagonal tile: key_local=4g+i valid iff <= r
      int k4 = g << 2;
      u0 = (k4 + 0 <= r) ? u0 : -3.0e38f;
      u1 = (k4 + 1 <= r) ? u1 : -3.0e38f;
      u2 = (k4 + 2 <= r) ? u2 : -3.0e38f;
      u3 = (k4 + 3 <= r) ? u3 : -3.0e38f;
    }
    float tmax = fmaxf(fmaxf(u0, u1), fmaxf(u2, u3));
    tmax = fmaxf(tmax, __shfl_xor(tmax, 16));
    tmax = fmaxf(tmax, __shfl_xor(tmax, 32));
    float p0, p1, p2, p3;
    if (__all(tmax <= mrun)) {
      p0 = EXP2F(u0 - mrun); p1 = EXP2F(u1 - mrun);
      p2 = EXP2F(u2 - mrun); p3 = EXP2F(u3 - mrun);
      lsum += (p0 + p1) + (p2 + p3);
    } else {
      float mn = fmaxf(mrun, tmax);
      float rs = EXP2F(mrun - mn);
      mrun = mn;
      p0 = EXP2F(u0 - mn); p1 = EXP2F(u1 - mn);
      p2 = EXP2F(u2 - mn); p3 = EXP2F(u3 - mn);
      lsum = lsum * rs + ((p0 + p1) + (p2 + p3));
#pragma unroll
      for (int dt = 0; dt < 4; ++dt) acc[dt] *= rs;
    }
    short4v pf;
    pf[0] = (short)f2b(p0); pf[1] = (short)f2b(p1);
    pf[2] = (short)f2b(p2); pf[3] = (short)f2b(p3);
    const int vsl = (g ^ (r >> 2)) << 3;
#pragma unroll
    for (int dt = 0; dt < 4; ++dt) {
      const short4v vf = *(const short4v*)(lvb + (16 * dt + r) * 32 + vsl);
      acc[dt] = __builtin_amdgcn_mfma_f32_16x16x16bf16_1k(vf, pf, acc[dt], 0, 0, 0);
    }
  };

  // prologue: stage tile 0, preload tile 1 into regs
  stload(0, kR1, vR1);
  stwrite(0, kR1, vR1);
  if (nm > 1) stload(1, kR1, vR1);
  __syncthreads();

  for (int m = 0; m < nm; ++m) {
    if (m + 2 < nm) stload(m + 2, kR2, vR2);   // issue early: latency under compute
    const int nl = mysteps - m * 4;
    const int bi = m & 1;
    if (nl > 0) micro(bi, 0, m * 4 + 0 == dloc);
    if (nl > 1) micro(bi, 1, m * 4 + 1 == dloc);
    if (nl > 2) micro(bi, 2, m * 4 + 2 == dloc);
    if (nl > 3) micro(bi, 3, m * 4 + 3 == dloc);
    if (m + 1 < nm) stwrite((m + 1) & 1, kR1, vR1);  // other buffer: safe pre-barrier
    __syncthreads();
    kR1 = kR2; vR1 = vR2;
  }

  lsum += __shfl_xor(lsum, 16);
  lsum += __shfl_xor(lsum, 32);

  const int slot = bx;  // slot id == block id by construction
  const int prow = wv * 16 + r;
  if (g == 0) {
    pml[slot * 256 + prow * 2 + 0] = mrun;
    pml[slot * 256 + prow * 2 + 1] = lsum;
  }
  float* pp = pacc + (size_t)slot * 8192 + prow * 64 + g * 4;
#pragma unroll
  for (int dt = 0; dt < 4; ++dt)
    *(float4v*)(pp + dt * 16) = acc[dt];
}

// ---- P3: combine split-K partials (two-pass, no register arrays) ----
__global__ __launch_bounds__(256) void combine_kernel(
    const float* __restrict__ pacc, const float* __restrict__ pml,
    float* __restrict__ out) {
  const int bx = blockIdx.x;          // (b*32 + st)*4 + rq
  const int rq = bx & 3, st = (bx >> 2) & 31, b = bx >> 7;
  const int g2 = st >> 2, nc = g2 + 1;
  const int sb = b * 144 + 2 * g2 * (g2 + 1) + (st - 4 * g2) * nc;
  const int t = threadIdx.x;
  const int row = rq * 32 + (t >> 3);
  const int d0 = (t & 7) * 8;

  float M = -3.0e38f;
  for (int p = 0; p < nc; ++p)
    M = fmaxf(M, pml[(sb + p) * 256 + row * 2]);
  float denom = 0.f;
  float4v v0 = {0.f, 0.f, 0.f, 0.f}, v1 = {0.f, 0.f, 0.f, 0.f};
  for (int p = 0; p < nc; ++p) {
    float m = pml[(sb + p) * 256 + row * 2];
    float l = pml[(sb + p) * 256 + row * 2 + 1];
    float wgt = EXP2F(m - M);
    denom += l * wgt;
    const float* ap = pacc + (size_t)(sb + p) * 8192 + row * 64 + d0;
    v0 += *(const float4v*)ap * wgt;
    v1 += *(const float4v*)(ap + 4) * wgt;
  }
  float inv = 1.0f / denom;
  float* op = out + ((size_t)(b * 4096 + st * 128 + row)) * 64 + d0;
  *(float4v*)op = v0 * inv;
  *(float4v*)(op + 4) = v1 * inv;
}

extern "C" void kernel_launch(void* const* d_in, const int* in_sizes, int n_in,
                              void* d_out, int out_size, void* d_ws, size_t ws_size,
                              hipStream_t stream) {
  const float* X  = (const float*)d_in[0];
  const float* Wq = (const float*)d_in[1];
  const float* bq = (const float*)d_in[2];
  const float* Wk = (const float*)d_in[3];
  const float* bk = (const float*)d_in[4];
  const float* Wv = (const float*)d_in[5];
  const float* bv = (const float*)d_in[6];
  float* out = (float*)d_out;

  ushort* Qb = (ushort*)d_ws;                  // [B*S][64] bf16 (scaled, exp2 dom)
  ushort* Kb = Qb + 4 * 4096 * 64;             // [B*S][64] bf16
  ushort* Vt = Kb + 4 * 4096 * 64;             // [B][64][S] bf16 (V transposed)
  ushort* Wt = Vt + 4 * 4096 * 64;             // [192][768] bf16
  float* bb  = (float*)(Wt + 192 * 768);       // [192] f32
  float* pml  = bb + 256;                      // [576][128][2] f32
  float* pacc = pml + 576 * 256;               // [576][128][64] f32 (~18.9MB)

  wpack_kernel<<<36, 256, 0, stream>>>(Wq, bq, Wk, bk, Wv, bv, Wt, bb);
  proj_kernel<<<512, 256, 0, stream>>>(X, Wt, bb, Qb, Kb, Vt);
  attn_kernel<<<576, 512, 0, stream>>>(Qb, Kb, Vt, pacc, pml);
  combine_kernel<<<512, 256, 0, stream>>>(pacc, pml, out);
}